// Round 1
// baseline (3259.250 us; speedup 1.0000x reference)
//
#include <hip/hip_runtime.h>
#include <math.h>

#define BM 64
#define BN 64
#define BK 16
#define PADA 4
#define PADB 4

// MODE 0: A[M][K], B[K][N]  (NN)
// MODE 1: A[K][M], B[K][N]  (TN)   -- for S = Q^T K, both stored [C][N]
// MODE 2: A[M][K], B[N][K]  (NT)   -- for OUT = V * w^T
template<int MODE>
__global__ __launch_bounds__(256) void gemm_f32(
    const float* __restrict__ A, const float* __restrict__ B,
    float* __restrict__ C, const float* __restrict__ bias,
    const float* __restrict__ addsrc,
    int M, int N, int K,
    long sA, long sB, long sC, long sAdd,
    float scale, int relu)
{
  __shared__ float As[BK][BM + PADA];
  __shared__ float Bs[BK][BN + PADB];
  const int tid = threadIdx.x;
  const int bx = blockIdx.x, by = blockIdx.y, bz = blockIdx.z;
  const int m0 = by * BM, n0 = bx * BN;
  A += (long)bz * sA;
  B += (long)bz * sB;
  C += (long)bz * sC;
  const float* addp = addsrc ? addsrc + (long)bz * sAdd : nullptr;
  const int tx = tid & 15, ty = tid >> 4;

  float acc[4][4];
#pragma unroll
  for (int i = 0; i < 4; i++)
#pragma unroll
    for (int j = 0; j < 4; j++) acc[i][j] = 0.f;

  for (int k0 = 0; k0 < K; k0 += BK) {
    // ---- load A tile into As[k][m]
    if (MODE == 0 || MODE == 2) {
      const int c = tid & 15, r0 = tid >> 4;
#pragma unroll
      for (int l = 0; l < 4; l++) {
        const int r = r0 + 16 * l;
        As[c][r] = A[(long)(m0 + r) * K + (k0 + c)];
      }
    } else {
      const int c = tid & 63, r0 = tid >> 6;
#pragma unroll
      for (int l = 0; l < 4; l++) {
        const int kk = r0 + 4 * l;
        As[kk][c] = A[(long)(k0 + kk) * M + (m0 + c)];
      }
    }
    // ---- load B tile into Bs[k][n]
    if (MODE == 2) {
      const int c = tid & 15, r0 = tid >> 4;
#pragma unroll
      for (int l = 0; l < 4; l++) {
        const int r = r0 + 16 * l;
        Bs[c][r] = B[(long)(n0 + r) * K + (k0 + c)];
      }
    } else {
      const int c = tid & 63, r0 = tid >> 6;
#pragma unroll
      for (int l = 0; l < 4; l++) {
        const int kk = r0 + 4 * l;
        Bs[kk][c] = B[(long)(k0 + kk) * N + (n0 + c)];
      }
    }
    __syncthreads();
#pragma unroll
    for (int kk = 0; kk < BK; kk++) {
      float a[4], b[4];
#pragma unroll
      for (int i = 0; i < 4; i++) a[i] = As[kk][ty * 4 + i];
#pragma unroll
      for (int j = 0; j < 4; j++) b[j] = Bs[kk][tx * 4 + j];
#pragma unroll
      for (int i = 0; i < 4; i++)
#pragma unroll
        for (int j = 0; j < 4; j++)
          acc[i][j] = fmaf(a[i], b[j], acc[i][j]);
    }
    __syncthreads();
  }

  // ---- epilogue
#pragma unroll
  for (int i = 0; i < 4; i++) {
    const int m = m0 + ty * 4 + i;
    const float bv = bias ? bias[m] : 0.f;
#pragma unroll
    for (int j = 0; j < 4; j++) {
      const int n = n0 + tx * 4 + j;
      float v = acc[i][j] * scale + bv;
      if (addp) v += addp[(long)m * N + n];
      if (relu) v = fmaxf(v, 0.f);
      C[(long)m * N + n] = v;
    }
  }
}

// b' = W2 @ b1 + b2   (512x512 * 512)
__global__ __launch_bounds__(256) void bias_combine(
    const float* __restrict__ W2, const float* __restrict__ b1,
    const float* __restrict__ b2, float* __restrict__ bout)
{
  const int o = blockIdx.x * 256 + threadIdx.x;
  if (o < 512) {
    float acc = b2[o];
    for (int t = 0; t < 512; t++) acc = fmaf(W2[(long)o * 512 + t], b1[t], acc);
    bout[o] = acc;
  }
}

#define NROW 1600

// Per-row: softmax + rank-based mask; overwrites S row with attn*mask.
// mask = 1 for s<0; (rank+1)^3 for s>=0 where rank = stable descending rank.
__global__ __launch_bounds__(256) void rowproc(float* __restrict__ S)
{
  __shared__ float sm[NROW];
  __shared__ float pv[NROW];
  __shared__ unsigned short pidx[NROW];
  __shared__ float wmask[NROW];
  __shared__ float redf[256];
  __shared__ int scanb[256];

  const int tid = threadIdx.x;
  float* srow = S + (long)blockIdx.x * NROW;

  // load row + max
  float lmax = -3.4e38f;
  for (int i = tid; i < NROW; i += 256) {
    const float v = srow[i];
    sm[i] = v;
    lmax = fmaxf(lmax, v);
  }
  redf[tid] = lmax;
  __syncthreads();
#pragma unroll
  for (int s = 128; s > 0; s >>= 1) {
    if (tid < s) redf[tid] = fmaxf(redf[tid], redf[tid + s]);
    __syncthreads();
  }
  const float rmax = redf[0];
  __syncthreads();

  // expsum
  float lsum = 0.f;
  for (int i = tid; i < NROW; i += 256) lsum += __expf(sm[i] - rmax);
  redf[tid] = lsum;
  __syncthreads();
#pragma unroll
  for (int s = 128; s > 0; s >>= 1) {
    if (tid < s) redf[tid] += redf[tid + s];
    __syncthreads();
  }
  const float Z = redf[0];

  // ---- compact non-negative values (order-preserving)
  const int c0 = min(tid * 7, NROW);
  const int c1 = min(c0 + 7, NROW);
  int cnt = 0;
  for (int i = c0; i < c1; i++) cnt += (sm[i] >= 0.f) ? 1 : 0;
  scanb[tid] = cnt;
  __syncthreads();
  for (int d = 1; d < 256; d <<= 1) {
    const int vme = scanb[tid];
    const int vnb = (tid >= d) ? scanb[tid - d] : 0;
    __syncthreads();
    scanb[tid] = vme + vnb;
    __syncthreads();
  }
  const int P = scanb[255];
  int ofs = scanb[tid] - cnt;  // exclusive prefix
  for (int i = c0; i < c1; i++) {
    if (sm[i] >= 0.f) {
      pv[ofs] = sm[i];
      pidx[ofs] = (unsigned short)i;
      ofs++;
    }
  }
  for (int i = tid; i < NROW; i += 256) wmask[i] = 1.f;
  __syncthreads();

  // ---- O(P^2) stable descending rank of positives
  for (int j = tid; j < P; j += 256) {
    const float vj = pv[j];
    int rank = 0;
    int i = 0;
    for (; i + 4 <= P; i += 4) {
      const float v0 = pv[i], v1 = pv[i + 1], v2 = pv[i + 2], v3 = pv[i + 3];
      rank += (int)(v0 > vj) + (int)(v1 > vj) + (int)(v2 > vj) + (int)(v3 > vj);
      rank += (int)((v0 == vj) & (i < j)) + (int)((v1 == vj) & (i + 1 < j)) +
              (int)((v2 == vj) & (i + 2 < j)) + (int)((v3 == vj) & (i + 3 < j));
    }
    for (; i < P; i++)
      rank += (int)(pv[i] > vj) + (int)((pv[i] == vj) & (i < j));
    const float r1 = (float)(rank + 1);
    wmask[pidx[j]] = r1 * r1 * r1;
  }
  __syncthreads();

  // ---- write attn * mask back
  const float invZ = 1.f / Z;
  for (int i = tid; i < NROW; i += 256) {
    srow[i] = __expf(sm[i] - rmax) * invZ * wmask[i];
  }
}

extern "C" void kernel_launch(void* const* d_in, const int* in_sizes, int n_in,
                              void* d_out, int out_size, void* d_ws, size_t ws_size,
                              hipStream_t stream)
{
  const int Bn = 8, Cc = 512, Nn = 1600;
  const float scale = 0.04419417382415922f;  // 1/sqrt(512)

  const float* x   = (const float*)d_in[0];
  const float* Wc  = (const float*)d_in[1];
  const float* bc  = (const float*)d_in[2];
  const float* Wq1 = (const float*)d_in[3];
  const float* bq1 = (const float*)d_in[4];
  const float* Wq2 = (const float*)d_in[5];
  const float* bq2 = (const float*)d_in[6];
  const float* Wk1 = (const float*)d_in[7];
  const float* bk1 = (const float*)d_in[8];
  const float* Wk2 = (const float*)d_in[9];
  const float* bk2 = (const float*)d_in[10];
  const float* Wv1 = (const float*)d_in[11];
  const float* bv1 = (const float*)d_in[12];
  const float* Wv2 = (const float*)d_in[13];
  const float* bv2 = (const float*)d_in[14];
  float* out = (float*)d_out;

  float* ws  = (float*)d_ws;
  float* Wqp = ws; ws += 512 * 512;
  float* Wkp = ws; ws += 512 * 512;
  float* Wvp = ws; ws += 512 * 512;
  float* bqp = ws; ws += 512;
  float* bkp = ws; ws += 512;
  float* bvp = ws; ws += 512;
  float* xc  = ws; ws += (long)Bn * Cc * Nn;
  float* Q   = ws; ws += (long)Bn * Cc * Nn;
  float* Km  = ws; ws += (long)Bn * Cc * Nn;
  float* V   = ws; ws += (long)Bn * Cc * Nn;
  float* S   = ws; ws += (long)Bn * Nn * Nn;

  const long sCN = (long)Cc * Nn;  // 819200
  const long sNN = (long)Nn * Nn;  // 2560000

  const dim3 blk(256);

  // combined weights W' = W2 @ W1, b' = W2 @ b1 + b2
  gemm_f32<0><<<dim3(8, 8, 1), blk, 0, stream>>>(Wq2, Wq1, Wqp, nullptr, nullptr,
                                                 512, 512, 512, 0, 0, 0, 0, 1.f, 0);
  gemm_f32<0><<<dim3(8, 8, 1), blk, 0, stream>>>(Wk2, Wk1, Wkp, nullptr, nullptr,
                                                 512, 512, 512, 0, 0, 0, 0, 1.f, 0);
  gemm_f32<0><<<dim3(8, 8, 1), blk, 0, stream>>>(Wv2, Wv1, Wvp, nullptr, nullptr,
                                                 512, 512, 512, 0, 0, 0, 0, 1.f, 0);
  bias_combine<<<dim3(2), blk, 0, stream>>>(Wq2, bq1, bq2, bqp);
  bias_combine<<<dim3(2), blk, 0, stream>>>(Wk2, bk1, bk2, bkp);
  bias_combine<<<dim3(2), blk, 0, stream>>>(Wv2, bv1, bv2, bvp);

  // xc = relu(Wc x + bc)
  gemm_f32<0><<<dim3(25, 8, 8), blk, 0, stream>>>(Wc, x, xc, bc, nullptr,
                                                  512, 1600, 512, 0, sCN, sCN, 0, 1.f, 1);
  // Q,K,V = W' xc + b'
  gemm_f32<0><<<dim3(25, 8, 8), blk, 0, stream>>>(Wqp, xc, Q, bqp, nullptr,
                                                  512, 1600, 512, 0, sCN, sCN, 0, 1.f, 0);
  gemm_f32<0><<<dim3(25, 8, 8), blk, 0, stream>>>(Wkp, xc, Km, bkp, nullptr,
                                                  512, 1600, 512, 0, sCN, sCN, 0, 1.f, 0);
  gemm_f32<0><<<dim3(25, 8, 8), blk, 0, stream>>>(Wvp, xc, V, bvp, nullptr,
                                                  512, 1600, 512, 0, sCN, sCN, 0, 1.f, 0);

  // S = scale * Q^T K   (per batch, [1600x1600])
  gemm_f32<1><<<dim3(25, 25, 8), blk, 0, stream>>>(Q, Km, S, nullptr, nullptr,
                                                   1600, 1600, 512, sCN, sCN, sNN, 0, scale, 0);
  // softmax + rank mask (overwrite S with attn*mask)
  rowproc<<<dim3(12800), blk, 0, stream>>>(S);

  // out[c][n] = sum_m V[c][m] * w[n][m] + xc[c][n]
  gemm_f32<2><<<dim3(25, 8, 8), blk, 0, stream>>>(V, S, out, nullptr, xc,
                                                  512, 1600, 1600, sCN, sNN, sCN, sCN, 1.f, 0);
}

// Round 2
// 1332.894 us; speedup vs baseline: 2.4452x; 2.4452x over previous
//
#include <hip/hip_runtime.h>
#include <math.h>

#define BM 64
#define BN 64
#define BK 16
#define PADA 4
#define PADB 4

// MODE 0: A[M][K], B[K][N]  (NN)
// MODE 1: A[K][M], B[K][N]  (TN)   -- for S = Q^T K, both stored [C][N]
// MODE 2: A[M][K], B[N][K]  (NT)   -- for OUT = V * w^T
template<int MODE>
__global__ __launch_bounds__(256) void gemm_f32(
    const float* __restrict__ A, const float* __restrict__ B,
    float* __restrict__ C, const float* __restrict__ bias,
    const float* __restrict__ addsrc,
    int M, int N, int K,
    long sA, long sB, long sC, long sAdd,
    float scale, int relu)
{
  __shared__ float As[BK][BM + PADA];
  __shared__ float Bs[BK][BN + PADB];
  const int tid = threadIdx.x;
  const int bx = blockIdx.x, by = blockIdx.y, bz = blockIdx.z;
  const int m0 = by * BM, n0 = bx * BN;
  A += (long)bz * sA;
  B += (long)bz * sB;
  C += (long)bz * sC;
  const float* addp = addsrc ? addsrc + (long)bz * sAdd : nullptr;
  const int tx = tid & 15, ty = tid >> 4;

  float acc[4][4];
#pragma unroll
  for (int i = 0; i < 4; i++)
#pragma unroll
    for (int j = 0; j < 4; j++) acc[i][j] = 0.f;

  for (int k0 = 0; k0 < K; k0 += BK) {
    // ---- load A tile into As[k][m]
    if (MODE == 0 || MODE == 2) {
      const int c = tid & 15, r0 = tid >> 4;
#pragma unroll
      for (int l = 0; l < 4; l++) {
        const int r = r0 + 16 * l;
        As[c][r] = A[(long)(m0 + r) * K + (k0 + c)];
      }
    } else {
      const int c = tid & 63, r0 = tid >> 6;
#pragma unroll
      for (int l = 0; l < 4; l++) {
        const int kk = r0 + 4 * l;
        As[kk][c] = A[(long)(k0 + kk) * M + (m0 + c)];
      }
    }
    // ---- load B tile into Bs[k][n]
    if (MODE == 2) {
      const int c = tid & 15, r0 = tid >> 4;
#pragma unroll
      for (int l = 0; l < 4; l++) {
        const int r = r0 + 16 * l;
        Bs[c][r] = B[(long)(n0 + r) * K + (k0 + c)];
      }
    } else {
      const int c = tid & 63, r0 = tid >> 6;
#pragma unroll
      for (int l = 0; l < 4; l++) {
        const int kk = r0 + 4 * l;
        Bs[kk][c] = B[(long)(k0 + kk) * N + (n0 + c)];
      }
    }
    __syncthreads();
#pragma unroll
    for (int kk = 0; kk < BK; kk++) {
      float a[4], b[4];
#pragma unroll
      for (int i = 0; i < 4; i++) a[i] = As[kk][ty * 4 + i];
#pragma unroll
      for (int j = 0; j < 4; j++) b[j] = Bs[kk][tx * 4 + j];
#pragma unroll
      for (int i = 0; i < 4; i++)
#pragma unroll
        for (int j = 0; j < 4; j++)
          acc[i][j] = fmaf(a[i], b[j], acc[i][j]);
    }
    __syncthreads();
  }

  // ---- epilogue
#pragma unroll
  for (int i = 0; i < 4; i++) {
    const int m = m0 + ty * 4 + i;
    const float bv = bias ? bias[m] : 0.f;
#pragma unroll
    for (int j = 0; j < 4; j++) {
      const int n = n0 + tx * 4 + j;
      float v = acc[i][j] * scale + bv;
      if (addp) v += addp[(long)m * N + n];
      if (relu) v = fmaxf(v, 0.f);
      C[(long)m * N + n] = v;
    }
  }
}

// b' = W2 @ b1 + b2   (512x512 * 512)
__global__ __launch_bounds__(256) void bias_combine(
    const float* __restrict__ W2, const float* __restrict__ b1,
    const float* __restrict__ b2, float* __restrict__ bout)
{
  const int o = blockIdx.x * 256 + threadIdx.x;
  if (o < 512) {
    float acc = b2[o];
    for (int t = 0; t < 512; t++) acc = fmaf(W2[(long)o * 512 + t], b1[t], acc);
    bout[o] = acc;
  }
}

#define NROW 1600
#define NB 1024
#define BOFF 3392  // (exp=106) << 5 : buckets cover 2^-21 .. 2^11

// Per-row: softmax + rank-based mask; overwrites S row with attn*mask.
// mask = 1 for s<0; (rank+1)^3 for s>=0 where rank = stable descending rank.
// Rank via bucket histogram + suffix scan + within-bucket O(g^2) refinement.
__global__ __launch_bounds__(256) void rowproc(float* __restrict__ S)
{
  __shared__ float sm[NROW];
  __shared__ float wmask[NROW];
  __shared__ unsigned short gidx[NROW];
  __shared__ int hist[NB];
  __shared__ int Rb[NB];   // rank base -> scatter cursor -> group end
  __shared__ int scA[256];
  __shared__ int scB[256];
  __shared__ float redf[256];

  const int tid = threadIdx.x;
  float* srow = S + (long)blockIdx.x * NROW;

  // ---- load row + max
  float lmax = -3.4e38f;
  for (int i = tid; i < NROW; i += 256) {
    const float v = srow[i];
    sm[i] = v;
    wmask[i] = 1.f;
    lmax = fmaxf(lmax, v);
  }
  redf[tid] = lmax;
  // zero histogram while we're here
#pragma unroll
  for (int j = 0; j < NB / 256; j++) hist[tid + 256 * j] = 0;
  __syncthreads();
#pragma unroll
  for (int s = 128; s > 0; s >>= 1) {
    if (tid < s) redf[tid] = fmaxf(redf[tid], redf[tid + s]);
    __syncthreads();
  }
  const float rmax = redf[0];
  __syncthreads();

  // ---- expsum + histogram of positives
  float lsum = 0.f;
  for (int i = tid; i < NROW; i += 256) {
    const float v = sm[i];
    lsum += __expf(v - rmax);
    if (v >= 0.f) {
      unsigned u = __float_as_uint(v) & 0x7fffffffu;  // -0.0 -> bin 0
      int b = (int)(u >> 18) - BOFF;
      b = max(0, min(NB - 1, b));
      atomicAdd(&hist[b], 1);
    }
  }
  redf[tid] = lsum;
  __syncthreads();
#pragma unroll
  for (int s = 128; s > 0; s >>= 1) {
    if (tid < s) redf[tid] += redf[tid + s];
    __syncthreads();
  }
  const float Z = redf[0];

  // ---- suffix scan over bins: Rb[b] = #elements in bins > b
  const int h0 = hist[4 * tid], h1 = hist[4 * tid + 1];
  const int h2 = hist[4 * tid + 2], h3 = hist[4 * tid + 3];
  const int local = h0 + h1 + h2 + h3;
  scA[tid] = local;
  __syncthreads();
  int* src = scA;
  int* dst = scB;
#pragma unroll
  for (int d = 1; d < 256; d <<= 1) {
    const int v = src[tid] + ((tid + d < 256) ? src[tid + d] : 0);
    dst[tid] = v;
    __syncthreads();
    int* t = src; src = dst; dst = t;
  }
  const int P = src[0];                 // total positives
  const int hi = src[tid] - local;      // count in threads > tid
  Rb[4 * tid + 3] = hi;
  Rb[4 * tid + 2] = hi + h3;
  Rb[4 * tid + 1] = hi + h3 + h2;
  Rb[4 * tid + 0] = hi + h3 + h2 + h1;
  __syncthreads();

  // ---- scatter positives into bin groups (order within group irrelevant)
  for (int i = tid; i < NROW; i += 256) {
    const float v = sm[i];
    if (v >= 0.f) {
      unsigned u = __float_as_uint(v) & 0x7fffffffu;
      int b = (int)(u >> 18) - BOFF;
      b = max(0, min(NB - 1, b));
      const int pos = atomicAdd(&Rb[b], 1);
      gidx[pos] = (unsigned short)i;
    }
  }
  __syncthreads();
  // now Rb[b] = group end; start = Rb[b] - hist[b]; rank base = start

  // ---- within-bucket refinement: exact stable descending rank
  for (int p = tid; p < P; p += 256) {
    const int ip = gidx[p];
    const float vp = sm[ip];
    unsigned u = __float_as_uint(vp) & 0x7fffffffu;
    int b = (int)(u >> 18) - BOFF;
    b = max(0, min(NB - 1, b));
    const int end = Rb[b];
    const int start = end - hist[b];
    int cnt = 0;
    for (int q = start; q < end; q++) {
      const int iq = gidx[q];
      const float vq = sm[iq];
      cnt += (int)((vq > vp) || ((vq == vp) && (iq < ip)));
    }
    const int rank = start + cnt;
    const float r1 = (float)(rank + 1);
    wmask[ip] = r1 * r1 * r1;
  }
  __syncthreads();

  // ---- write attn * mask back
  const float invZ = 1.f / Z;
  for (int i = tid; i < NROW; i += 256) {
    srow[i] = __expf(sm[i] - rmax) * invZ * wmask[i];
  }
}

extern "C" void kernel_launch(void* const* d_in, const int* in_sizes, int n_in,
                              void* d_out, int out_size, void* d_ws, size_t ws_size,
                              hipStream_t stream)
{
  const int Bn = 8, Cc = 512, Nn = 1600;
  const float scale = 0.04419417382415922f;  // 1/sqrt(512)

  const float* x   = (const float*)d_in[0];
  const float* Wc  = (const float*)d_in[1];
  const float* bc  = (const float*)d_in[2];
  const float* Wq1 = (const float*)d_in[3];
  const float* bq1 = (const float*)d_in[4];
  const float* Wq2 = (const float*)d_in[5];
  const float* bq2 = (const float*)d_in[6];
  const float* Wk1 = (const float*)d_in[7];
  const float* bk1 = (const float*)d_in[8];
  const float* Wk2 = (const float*)d_in[9];
  const float* bk2 = (const float*)d_in[10];
  const float* Wv1 = (const float*)d_in[11];
  const float* bv1 = (const float*)d_in[12];
  const float* Wv2 = (const float*)d_in[13];
  const float* bv2 = (const float*)d_in[14];
  float* out = (float*)d_out;

  float* ws  = (float*)d_ws;
  float* Wqp = ws; ws += 512 * 512;
  float* Wkp = ws; ws += 512 * 512;
  float* Wvp = ws; ws += 512 * 512;
  float* bqp = ws; ws += 512;
  float* bkp = ws; ws += 512;
  float* bvp = ws; ws += 512;
  float* xc  = ws; ws += (long)Bn * Cc * Nn;
  float* Q   = ws; ws += (long)Bn * Cc * Nn;
  float* Km  = ws; ws += (long)Bn * Cc * Nn;
  float* V   = ws; ws += (long)Bn * Cc * Nn;
  float* S   = ws; ws += (long)Bn * Nn * Nn;

  const long sCN = (long)Cc * Nn;  // 819200
  const long sNN = (long)Nn * Nn;  // 2560000

  const dim3 blk(256);

  // combined weights W' = W2 @ W1, b' = W2 @ b1 + b2
  gemm_f32<0><<<dim3(8, 8, 1), blk, 0, stream>>>(Wq2, Wq1, Wqp, nullptr, nullptr,
                                                 512, 512, 512, 0, 0, 0, 0, 1.f, 0);
  gemm_f32<0><<<dim3(8, 8, 1), blk, 0, stream>>>(Wk2, Wk1, Wkp, nullptr, nullptr,
                                                 512, 512, 512, 0, 0, 0, 0, 1.f, 0);
  gemm_f32<0><<<dim3(8, 8, 1), blk, 0, stream>>>(Wv2, Wv1, Wvp, nullptr, nullptr,
                                                 512, 512, 512, 0, 0, 0, 0, 1.f, 0);
  bias_combine<<<dim3(2), blk, 0, stream>>>(Wq2, bq1, bq2, bqp);
  bias_combine<<<dim3(2), blk, 0, stream>>>(Wk2, bk1, bk2, bkp);
  bias_combine<<<dim3(2), blk, 0, stream>>>(Wv2, bv1, bv2, bvp);

  // xc = relu(Wc x + bc)
  gemm_f32<0><<<dim3(25, 8, 8), blk, 0, stream>>>(Wc, x, xc, bc, nullptr,
                                                  512, 1600, 512, 0, sCN, sCN, 0, 1.f, 1);
  // Q,K,V = W' xc + b'
  gemm_f32<0><<<dim3(25, 8, 8), blk, 0, stream>>>(Wqp, xc, Q, bqp, nullptr,
                                                  512, 1600, 512, 0, sCN, sCN, 0, 1.f, 0);
  gemm_f32<0><<<dim3(25, 8, 8), blk, 0, stream>>>(Wkp, xc, Km, bkp, nullptr,
                                                  512, 1600, 512, 0, sCN, sCN, 0, 1.f, 0);
  gemm_f32<0><<<dim3(25, 8, 8), blk, 0, stream>>>(Wvp, xc, V, bvp, nullptr,
                                                  512, 1600, 512, 0, sCN, sCN, 0, 1.f, 0);

  // S = scale * Q^T K   (per batch, [1600x1600])
  gemm_f32<1><<<dim3(25, 25, 8), blk, 0, stream>>>(Q, Km, S, nullptr, nullptr,
                                                   1600, 1600, 512, sCN, sCN, sNN, 0, scale, 0);
  // softmax + rank mask (overwrite S with attn*mask)
  rowproc<<<dim3(12800), blk, 0, stream>>>(S);

  // out[c][n] = sum_m V[c][m] * w[n][m] + xc[c][n]
  gemm_f32<2><<<dim3(25, 8, 8), blk, 0, stream>>>(V, S, out, nullptr, xc,
                                                  512, 1600, 1600, sCN, sNN, sCN, sCN, 1.f, 0);
}

// Round 3
// 868.351 us; speedup vs baseline: 3.7534x; 1.5350x over previous
//
#include <hip/hip_runtime.h>
#include <math.h>

typedef short short8 __attribute__((ext_vector_type(8)));
typedef float f32x16 __attribute__((ext_vector_type(16)));

__device__ __forceinline__ unsigned short f2bf(float f) {
  unsigned u = __float_as_uint(f);
  unsigned r = u + 0x7fffu + ((u >> 16) & 1u);
  return (unsigned short)(r >> 16);
}
__device__ __forceinline__ float bf2f(unsigned short s) {
  return __uint_as_float(((unsigned)s) << 16);
}
__device__ __forceinline__ void gload_lds16(const void* g, void* l) {
  __builtin_amdgcn_global_load_lds(
      (const __attribute__((address_space(1))) unsigned int*)g,
      (__attribute__((address_space(3))) unsigned int*)l, 16, 0, 0);
}

#define TM 128
#define TN 128
#define TK 32

// NT MFMA GEMM: A [M][K] (ld=ldA), B [N][K] (ld=ldB), both as NSPLIT bf16 planes.
// acc = sum over split products. MODE: 0=XC 1=QKV 2=S 3=OUT
template<int NSPLIT, int MODE>
__global__ __launch_bounds__(256) void mfma_gemm(
    const unsigned short* __restrict__ A0, const unsigned short* __restrict__ A1,
    const unsigned short* __restrict__ A2,
    const unsigned short* __restrict__ B0, const unsigned short* __restrict__ B1,
    const unsigned short* __restrict__ B2,
    int M, int N, int K, int ldA, int ldB, long sA, long sB,
    const float* __restrict__ bias, float alpha,
    float* __restrict__ outF, long sOutF,
    unsigned short* __restrict__ P0, unsigned short* __restrict__ P1,
    unsigned short* __restrict__ P2, long sP,
    unsigned short* __restrict__ R0, unsigned short* __restrict__ R1,
    unsigned short* __restrict__ R2, long sR,
    unsigned short* __restrict__ V0, unsigned short* __restrict__ V1, long sV,
    unsigned short* __restrict__ xcn, long sXcn)
{
  __shared__ __align__(16) unsigned short As[NSPLIT][128 * 32];
  __shared__ __align__(16) unsigned short Bs[NSPLIT][128 * 32];

  const int tid = threadIdx.x;
  const int bz = blockIdx.z;
  const int m0 = blockIdx.y * TM, n0 = blockIdx.x * TN;
  const int lane = tid & 63, w = tid >> 6;
  const int wm = w >> 1, wn = w & 1;
  const int g = lane >> 5, lr = lane & 31;

  // staging mapping: issue i covers rows i*64 + (tid>>2), 16B slot tid&3 (swizzled)
  const int str = tid >> 2, sts = tid & 3;
  long aoff[2], boff[2];
#pragma unroll
  for (int i = 0; i < 2; i++) {
    const int r = i * 64 + str;
    const int swc = (sts ^ (r & 3)) * 8;
    aoff[i] = (long)min(m0 + r, M - 1) * ldA + swc;
    boff[i] = (long)min(n0 + r, N - 1) * ldB + swc;
  }
  const unsigned short* Ap[3];
  const unsigned short* Bp[3];
  Ap[0] = A0 + bz * sA; Bp[0] = B0 + bz * sB;
  Ap[1] = A1 + bz * sA; Bp[1] = B1 + bz * sB;
  Ap[2] = (NSPLIT == 3) ? A2 + bz * sA : Ap[0];
  Bp[2] = (NSPLIT == 3) ? B2 + bz * sB : Bp[0];

  f32x16 acc[2][2];
#pragma unroll
  for (int i = 0; i < 2; i++)
#pragma unroll
    for (int j = 0; j < 2; j++)
#pragma unroll
      for (int e = 0; e < 16; e++) acc[i][j][e] = 0.f;

  for (int k0 = 0; k0 < K; k0 += TK) {
#pragma unroll
    for (int p = 0; p < NSPLIT; p++)
#pragma unroll
      for (int i = 0; i < 2; i++) {
        gload_lds16(Ap[p] + aoff[i] + k0, (char*)&As[p][0] + i * 4096 + tid * 16);
        gload_lds16(Bp[p] + boff[i] + k0, (char*)&Bs[p][0] + i * 4096 + tid * 16);
      }
    __syncthreads();
#pragma unroll
    for (int kk = 0; kk < 2; kk++) {
      short8 af[2][3], bf[2][3];
#pragma unroll
      for (int i = 0; i < 2; i++) {
        const int rowa = wm * 64 + i * 32 + lr;
        const int sla = ((kk * 2 + g) ^ (rowa & 3)) * 8;
#pragma unroll
        for (int p = 0; p < NSPLIT; p++)
          af[i][p] = *(const short8*)&As[p][rowa * 32 + sla];
        const int rowb = wn * 64 + i * 32 + lr;
        const int slb = ((kk * 2 + g) ^ (rowb & 3)) * 8;
#pragma unroll
        for (int p = 0; p < NSPLIT; p++)
          bf[i][p] = *(const short8*)&Bs[p][rowb * 32 + slb];
      }
#pragma unroll
      for (int i = 0; i < 2; i++)
#pragma unroll
        for (int j = 0; j < 2; j++) {
          acc[i][j] = __builtin_amdgcn_mfma_f32_32x32x16_bf16(af[i][0], bf[j][0], acc[i][j], 0, 0, 0);
          acc[i][j] = __builtin_amdgcn_mfma_f32_32x32x16_bf16(af[i][0], bf[j][1], acc[i][j], 0, 0, 0);
          acc[i][j] = __builtin_amdgcn_mfma_f32_32x32x16_bf16(af[i][1], bf[j][0], acc[i][j], 0, 0, 0);
          if (NSPLIT == 3) {
            acc[i][j] = __builtin_amdgcn_mfma_f32_32x32x16_bf16(af[i][1], bf[j][1], acc[i][j], 0, 0, 0);
            acc[i][j] = __builtin_amdgcn_mfma_f32_32x32x16_bf16(af[i][0], bf[j][2], acc[i][j], 0, 0, 0);
            acc[i][j] = __builtin_amdgcn_mfma_f32_32x32x16_bf16(af[i][2], bf[j][0], acc[i][j], 0, 0, 0);
          }
        }
    }
    __syncthreads();
  }

  // epilogue: row = m0+wm*64+i*32 + rq*8 + g*4 + t ; col = n0+wn*64+j*32+lr
#pragma unroll
  for (int i = 0; i < 2; i++)
#pragma unroll
    for (int j = 0; j < 2; j++) {
      const int cb = n0 + wn * 64 + j * 32;
      const int col = cb + lr;
#pragma unroll
      for (int rq = 0; rq < 4; rq++)
#pragma unroll
        for (int t = 0; t < 4; t++) {
          const int reg = rq * 4 + t;
          const int row = m0 + wm * 64 + i * 32 + rq * 8 + g * 4 + t;
          float v = acc[i][j][reg];
          if (MODE == 0) {  // XC: relu, 3-plane xcT [n][c] + bf16 xc_cn [c][n]
            if (row < M) {
              v += bias[col];
              v = fmaxf(v, 0.f);
              const unsigned short h = f2bf(v); const float hf = bf2f(h);
              const unsigned short m_ = f2bf(v - hf); const float mf = bf2f(m_);
              const unsigned short l = f2bf(v - hf - mf);
              const long o = bz * sP + (long)row * 512 + col;
              P0[o] = h; P1[o] = m_; P2[o] = l;
              xcn[bz * sXcn + (long)col * 1600 + row] = h;
            }
          } else if (MODE == 1) {  // QKV
            if (row < M) {
              v += bias[col];
              if (cb < 512) {
                const unsigned short h = f2bf(v); const float hf = bf2f(h);
                const unsigned short m_ = f2bf(v - hf); const float mf = bf2f(m_);
                const unsigned short l = f2bf(v - hf - mf);
                const long o = bz * sP + (long)row * 512 + col;
                P0[o] = h; P1[o] = m_; P2[o] = l;
              } else if (cb < 1024) {
                const unsigned short h = f2bf(v); const float hf = bf2f(h);
                const unsigned short m_ = f2bf(v - hf); const float mf = bf2f(m_);
                const unsigned short l = f2bf(v - hf - mf);
                const long o = bz * sR + (long)row * 512 + (col - 512);
                R0[o] = h; R1[o] = m_; R2[o] = l;
              } else {
                const unsigned short h = f2bf(v);
                const unsigned short l = f2bf(v - bf2f(h));
                const long o = bz * sV + (long)(col - 1024) * 1600 + row;
                V0[o] = h; V1[o] = l;
              }
            }
          } else if (MODE == 2) {  // S
            if (row < M && col < N)
              outF[bz * sOutF + (long)row * 1600 + col] = v * alpha;
          } else {  // OUT: += residual
            if (col < N) {
              v += bf2f(xcn[bz * sXcn + (long)row * 1600 + col]);
              outF[bz * sOutF + (long)row * 1600 + col] = v;
            }
          }
        }
    }
}

// x [B][C][N] f32 -> xT planes [B][N][C] bf16 h/m/l
__global__ __launch_bounds__(256) void transpose_split_x(
    const float* __restrict__ x, unsigned short* __restrict__ X0,
    unsigned short* __restrict__ X1, unsigned short* __restrict__ X2)
{
  __shared__ float t[32][33];
  const int bz = blockIdx.z;
  const int n0 = blockIdx.x * 32, c0 = blockIdx.y * 32;
  const int tx = threadIdx.x & 31, ty = threadIdx.x >> 5;
  const float* xb = x + (long)bz * 512 * 1600;
#pragma unroll
  for (int k = 0; k < 4; k++)
    t[ty + k * 8][tx] = xb[(long)(c0 + ty + k * 8) * 1600 + n0 + tx];
  __syncthreads();
  const long ob = (long)bz * 1600 * 512;
#pragma unroll
  for (int k = 0; k < 4; k++) {
    const float v = t[tx][ty + k * 8];
    const unsigned short h = f2bf(v); const float hf = bf2f(h);
    const unsigned short m_ = f2bf(v - hf); const float mf = bf2f(m_);
    const unsigned short l = f2bf(v - hf - mf);
    const long o = ob + (long)(n0 + ty + k * 8) * 512 + c0 + tx;
    X0[o] = h; X1[o] = m_; X2[o] = l;
  }
}

__global__ __launch_bounds__(256) void split3_mat(
    const float* __restrict__ W, unsigned short* __restrict__ H,
    unsigned short* __restrict__ Mp, unsigned short* __restrict__ L, int n)
{
  const int i = blockIdx.x * 256 + threadIdx.x;
  if (i < n) {
    const float v = W[i];
    const unsigned short h = f2bf(v); const float hf = bf2f(h);
    const unsigned short m_ = f2bf(v - hf); const float mf = bf2f(m_);
    H[i] = h; Mp[i] = m_; L[i] = f2bf(v - hf - mf);
  }
}

// W' = W2 @ W1 (512^3, fp32 vector), split-written into planes at row offset
__global__ __launch_bounds__(256) void combine_gemm(
    const float* __restrict__ A, const float* __restrict__ B,
    unsigned short* __restrict__ H, unsigned short* __restrict__ Mp,
    unsigned short* __restrict__ L, int rowoff)
{
  __shared__ float As[16][68];
  __shared__ float Bs[16][68];
  const int tid = threadIdx.x;
  const int m0 = blockIdx.y * 64, n0 = blockIdx.x * 64;
  const int tx = tid & 15, ty = tid >> 4;
  float acc[4][4];
#pragma unroll
  for (int i = 0; i < 4; i++)
#pragma unroll
    for (int j = 0; j < 4; j++) acc[i][j] = 0.f;
  for (int k0 = 0; k0 < 512; k0 += 16) {
    {
      const int c = tid & 15, r0 = tid >> 4;
#pragma unroll
      for (int l = 0; l < 4; l++)
        As[c][r0 + 16 * l] = A[(long)(m0 + r0 + 16 * l) * 512 + (k0 + c)];
      const int c2 = tid & 63, r2 = tid >> 6;
#pragma unroll
      for (int l = 0; l < 4; l++)
        Bs[r2 + 4 * l][c2] = B[(long)(k0 + r2 + 4 * l) * 512 + (n0 + c2)];
    }
    __syncthreads();
#pragma unroll
    for (int kk = 0; kk < 16; kk++) {
      float a[4], b[4];
#pragma unroll
      for (int i = 0; i < 4; i++) a[i] = As[kk][ty * 4 + i];
#pragma unroll
      for (int j = 0; j < 4; j++) b[j] = Bs[kk][tx * 4 + j];
#pragma unroll
      for (int i = 0; i < 4; i++)
#pragma unroll
        for (int j = 0; j < 4; j++) acc[i][j] = fmaf(a[i], b[j], acc[i][j]);
    }
    __syncthreads();
  }
#pragma unroll
  for (int i = 0; i < 4; i++) {
    const int m = rowoff + m0 + ty * 4 + i;
#pragma unroll
    for (int j = 0; j < 4; j++) {
      const int n = n0 + tx * 4 + j;
      const float v = acc[i][j];
      const unsigned short h = f2bf(v); const float hf = bf2f(h);
      const unsigned short m_ = f2bf(v - hf); const float mf = bf2f(m_);
      const long o = (long)m * 512 + n;
      H[o] = h; Mp[o] = m_; L[o] = f2bf(v - hf - mf);
    }
  }
}

__global__ __launch_bounds__(256) void bias_combine(
    const float* __restrict__ W2, const float* __restrict__ b1,
    const float* __restrict__ b2, float* __restrict__ bout)
{
  const int o = blockIdx.x * 256 + threadIdx.x;
  if (o < 512) {
    float acc = b2[o];
    for (int t = 0; t < 512; t++) acc = fmaf(W2[(long)o * 512 + t], b1[t], acc);
    bout[o] = acc;
  }
}

#define NROW 1600
#define NB 1024
#define BOFF 3392

// softmax + rank mask; reads S row fp32, writes w = attn*mask as TWO bf16 planes
// in place: row n occupies bf16[0..1599]=h, bf16[1600..3199]=l of the old fp32 row.
__global__ __launch_bounds__(256) void rowproc(float* __restrict__ S)
{
  __shared__ float sm[NROW];
  __shared__ float wmask[NROW];
  __shared__ unsigned short gidx[NROW];
  __shared__ int hist[NB];
  __shared__ int Rb[NB];
  __shared__ int scA[256];
  __shared__ int scB[256];
  __shared__ float redf[256];

  const int tid = threadIdx.x;
  float* srow = S + (long)blockIdx.x * NROW;

  float lmax = -3.4e38f;
  for (int i = tid; i < NROW; i += 256) {
    const float v = srow[i];
    sm[i] = v;
    wmask[i] = 1.f;
    lmax = fmaxf(lmax, v);
  }
  redf[tid] = lmax;
#pragma unroll
  for (int j = 0; j < NB / 256; j++) hist[tid + 256 * j] = 0;
  __syncthreads();
#pragma unroll
  for (int s = 128; s > 0; s >>= 1) {
    if (tid < s) redf[tid] = fmaxf(redf[tid], redf[tid + s]);
    __syncthreads();
  }
  const float rmax = redf[0];
  __syncthreads();

  float lsum = 0.f;
  for (int i = tid; i < NROW; i += 256) {
    const float v = sm[i];
    lsum += __expf(v - rmax);
    if (v >= 0.f) {
      unsigned u = __float_as_uint(v) & 0x7fffffffu;
      int b = (int)(u >> 18) - BOFF;
      b = max(0, min(NB - 1, b));
      atomicAdd(&hist[b], 1);
    }
  }
  redf[tid] = lsum;
  __syncthreads();
#pragma unroll
  for (int s = 128; s > 0; s >>= 1) {
    if (tid < s) redf[tid] += redf[tid + s];
    __syncthreads();
  }
  const float Z = redf[0];

  const int h0 = hist[4 * tid], h1 = hist[4 * tid + 1];
  const int h2 = hist[4 * tid + 2], h3 = hist[4 * tid + 3];
  const int local = h0 + h1 + h2 + h3;
  scA[tid] = local;
  __syncthreads();
  int* src = scA;
  int* dst = scB;
#pragma unroll
  for (int d = 1; d < 256; d <<= 1) {
    const int v = src[tid] + ((tid + d < 256) ? src[tid + d] : 0);
    dst[tid] = v;
    __syncthreads();
    int* tp = src; src = dst; dst = tp;
  }
  const int P = src[0];
  const int hi = src[tid] - local;
  Rb[4 * tid + 3] = hi;
  Rb[4 * tid + 2] = hi + h3;
  Rb[4 * tid + 1] = hi + h3 + h2;
  Rb[4 * tid + 0] = hi + h3 + h2 + h1;
  __syncthreads();

  for (int i = tid; i < NROW; i += 256) {
    const float v = sm[i];
    if (v >= 0.f) {
      unsigned u = __float_as_uint(v) & 0x7fffffffu;
      int b = (int)(u >> 18) - BOFF;
      b = max(0, min(NB - 1, b));
      gidx[atomicAdd(&Rb[b], 1)] = (unsigned short)i;
    }
  }
  __syncthreads();

  for (int p = tid; p < P; p += 256) {
    const int ip = gidx[p];
    const float vp = sm[ip];
    unsigned u = __float_as_uint(vp) & 0x7fffffffu;
    int b = (int)(u >> 18) - BOFF;
    b = max(0, min(NB - 1, b));
    const int end = Rb[b];
    const int start = end - hist[b];
    int cnt = 0;
    for (int q = start; q < end; q++) {
      const int iq = gidx[q];
      const float vq = sm[iq];
      cnt += (int)((vq > vp) || ((vq == vp) && (iq < ip)));
    }
    const float r1 = (float)(start + cnt + 1);
    wmask[ip] = r1 * r1 * r1;
  }
  __syncthreads();

  const float invZ = 1.f / Z;
  unsigned short* wrow = (unsigned short*)srow;
  for (int i = tid; i < NROW; i += 256) {
    const float val = __expf(sm[i] - rmax) * invZ * wmask[i];
    const unsigned short h = f2bf(val);
    wrow[i] = h;
    wrow[NROW + i] = f2bf(val - bf2f(h));
  }
}

extern "C" void kernel_launch(void* const* d_in, const int* in_sizes, int n_in,
                              void* d_out, int out_size, void* d_ws, size_t ws_size,
                              hipStream_t stream)
{
  const float scale = 0.04419417382415922f;  // 1/sqrt(512)
  const long sCN = 819200L;                  // 512*1600
  const long sNN = 2560000L;                 // 1600*1600
  const long ePlane = 8L * sCN;              // elems per bf16 plane (batched)

  const float* x   = (const float*)d_in[0];
  const float* Wc  = (const float*)d_in[1];
  const float* bc  = (const float*)d_in[2];
  const float* Wq1 = (const float*)d_in[3];
  const float* bq1 = (const float*)d_in[4];
  const float* Wq2 = (const float*)d_in[5];
  const float* bq2 = (const float*)d_in[6];
  const float* Wk1 = (const float*)d_in[7];
  const float* bk1 = (const float*)d_in[8];
  const float* Wk2 = (const float*)d_in[9];
  const float* bk2 = (const float*)d_in[10];
  const float* Wv1 = (const float*)d_in[11];
  const float* bv1 = (const float*)d_in[12];
  const float* Wv2 = (const float*)d_in[13];
  const float* bv2 = (const float*)d_in[14];
  float* out = (float*)d_out;

  char* p = (char*)d_ws;
  auto carve = [&](size_t bytes) { char* r = p; p += (bytes + 255) & ~255UL; return r; };

  float* S = (float*)carve(8L * sNN * 4);  // S fp32; also hosts xT planes early, w planes late
  unsigned short* Xh = (unsigned short*)S;
  unsigned short* Xm = Xh + ePlane;
  unsigned short* Xl = Xm + ePlane;
  unsigned short* xcTh = (unsigned short*)carve(ePlane * 2);
  unsigned short* xcTm = (unsigned short*)carve(ePlane * 2);
  unsigned short* xcTl = (unsigned short*)carve(ePlane * 2);
  unsigned short* QTh = (unsigned short*)carve(ePlane * 2);
  unsigned short* QTm = (unsigned short*)carve(ePlane * 2);
  unsigned short* QTl = (unsigned short*)carve(ePlane * 2);
  unsigned short* KTh = (unsigned short*)carve(ePlane * 2);
  unsigned short* KTm = (unsigned short*)carve(ePlane * 2);
  unsigned short* KTl = (unsigned short*)carve(ePlane * 2);
  unsigned short* Vh = (unsigned short*)carve(ePlane * 2);
  unsigned short* Vl = (unsigned short*)carve(ePlane * 2);
  unsigned short* xc_cn = (unsigned short*)carve(ePlane * 2);
  unsigned short* Wch = (unsigned short*)carve(512L * 512 * 2);
  unsigned short* Wcm = (unsigned short*)carve(512L * 512 * 2);
  unsigned short* Wcl = (unsigned short*)carve(512L * 512 * 2);
  unsigned short* Wh = (unsigned short*)carve(1536L * 512 * 2);
  unsigned short* Wm = (unsigned short*)carve(1536L * 512 * 2);
  unsigned short* Wl = (unsigned short*)carve(1536L * 512 * 2);
  float* bqkv = (float*)carve(1536L * 4);

  // prep: x transpose+split, Wc split, combined weights/biases
  transpose_split_x<<<dim3(50, 16, 8), 256, 0, stream>>>(x, Xh, Xm, Xl);
  split3_mat<<<dim3(1024), 256, 0, stream>>>(Wc, Wch, Wcm, Wcl, 512 * 512);
  combine_gemm<<<dim3(8, 8), 256, 0, stream>>>(Wq2, Wq1, Wh, Wm, Wl, 0);
  combine_gemm<<<dim3(8, 8), 256, 0, stream>>>(Wk2, Wk1, Wh, Wm, Wl, 512);
  combine_gemm<<<dim3(8, 8), 256, 0, stream>>>(Wv2, Wv1, Wh, Wm, Wl, 1024);
  bias_combine<<<dim3(2), 256, 0, stream>>>(Wq2, bq1, bq2, bqkv);
  bias_combine<<<dim3(2), 256, 0, stream>>>(Wk2, bk1, bk2, bqkv + 512);
  bias_combine<<<dim3(2), 256, 0, stream>>>(Wv2, bv1, bv2, bqkv + 1024);

  // xc = relu(xT . Wc^T + bc): [1600][512], writes xcT planes + xc_cn
  mfma_gemm<3, 0><<<dim3(4, 13, 8), 256, 0, stream>>>(
      Xh, Xm, Xl, Wch, Wcm, Wcl, 1600, 512, 512, 512, 512, sCN, 0L, bc, 1.f,
      nullptr, 0L, xcTh, xcTm, xcTl, sCN,
      nullptr, nullptr, nullptr, 0L, nullptr, nullptr, 0L, xc_cn, sCN);

  // fused QKV: [1600][1536]
  mfma_gemm<3, 1><<<dim3(12, 13, 8), 256, 0, stream>>>(
      xcTh, xcTm, xcTl, Wh, Wm, Wl, 1600, 1536, 512, 512, 512, sCN, 0L, bqkv, 1.f,
      nullptr, 0L, QTh, QTm, QTl, sCN, KTh, KTm, KTl, sCN, Vh, Vl, sCN, nullptr, 0L);

  // S = scale * QT . KT^T : [1600][1600] fp32
  mfma_gemm<3, 2><<<dim3(13, 13, 8), 256, 0, stream>>>(
      QTh, QTm, QTl, KTh, KTm, KTl, 1600, 1600, 512, 512, 512, sCN, sCN, nullptr, scale,
      S, sNN, nullptr, nullptr, nullptr, 0L,
      nullptr, nullptr, nullptr, 0L, nullptr, nullptr, 0L, nullptr, 0L);

  // softmax + rank mask; writes w h/l planes in place over S
  rowproc<<<dim3(12800), 256, 0, stream>>>(S);

  // out = V . w^T + xc : [512][1600] fp32 -> d_out
  mfma_gemm<2, 3><<<dim3(13, 4, 8), 256, 0, stream>>>(
      Vh, Vl, nullptr, (unsigned short*)S, (unsigned short*)S + 1600, nullptr,
      512, 1600, 1600, 1600, 3200, sCN, 2L * sNN, nullptr, 1.f,
      out, sCN, nullptr, nullptr, nullptr, 0L,
      nullptr, nullptr, nullptr, 0L, nullptr, nullptr, 0L, xc_cn, sCN);
}

// Round 4
// 753.063 us; speedup vs baseline: 4.3280x; 1.1531x over previous
//
#include <hip/hip_runtime.h>
#include <math.h>

typedef short short8 __attribute__((ext_vector_type(8)));
typedef float f32x16 __attribute__((ext_vector_type(16)));

__device__ __forceinline__ unsigned short f2bf(float f) {
  unsigned u = __float_as_uint(f);
  unsigned r = u + 0x7fffu + ((u >> 16) & 1u);
  return (unsigned short)(r >> 16);
}
__device__ __forceinline__ float bf2f(unsigned short s) {
  return __uint_as_float(((unsigned)s) << 16);
}
__device__ __forceinline__ void gload_lds16(const void* g, void* l) {
  __builtin_amdgcn_global_load_lds(
      (const __attribute__((address_space(1))) unsigned int*)g,
      (__attribute__((address_space(3))) unsigned int*)l, 16, 0, 0);
}

#define TM 128
#define TN 128
#define TK 32
#define GH 7  // y-tiles grouped per rasterization column (L2 locality)

// NT MFMA GEMM: A [M][K] (ld=ldA), B [N][K] (ld=ldB), both as NSPLIT bf16 planes.
// 1D grid = GX*GY*GZ blocks (divisible by 8), XCD-chunked + grouped raster.
// MODE: 0=XC 1=QKV 2=S 3=OUT
template<int NSPLIT, int MODE>
__global__ __launch_bounds__(256) void mfma_gemm(
    const unsigned short* __restrict__ A0, const unsigned short* __restrict__ A1,
    const unsigned short* __restrict__ A2,
    const unsigned short* __restrict__ B0, const unsigned short* __restrict__ B1,
    const unsigned short* __restrict__ B2,
    int GX, int GY,
    int M, int N, int K, int ldA, int ldB, long sA, long sB,
    const float* __restrict__ bias, float alpha,
    float* __restrict__ outF, long sOutF,
    unsigned short* __restrict__ P0, unsigned short* __restrict__ P1,
    unsigned short* __restrict__ P2, long sP,
    unsigned short* __restrict__ R0, unsigned short* __restrict__ R1,
    unsigned short* __restrict__ R2, long sR,
    unsigned short* __restrict__ V0, unsigned short* __restrict__ V1, long sV,
    unsigned short* __restrict__ xcn, long sXcn)
{
  __shared__ __align__(16) unsigned short As[NSPLIT][128 * 32];
  __shared__ __align__(16) unsigned short Bs[NSPLIT][128 * 32];

  const int tid = threadIdx.x;

  // ---- XCD-chunked bijective remap (total % 8 == 0) + grouped raster decode
  const int total = GX * GY * ((int)gridDim.x / (GX * GY));
  const int q = total >> 3;
  const int wg = blockIdx.x;
  const int c = (wg & 7) * q + (wg >> 3);
  const int pb = GX * GY;
  const int bz = c / pb;
  int r = c - bz * pb;
  const int gy = r / (GH * GX);
  int rr = r - gy * (GH * GX);
  const int hh = min(GH, GY - gy * GH);
  const int xt = rr / hh;
  const int yt = gy * GH + (rr - xt * hh);

  const int m0 = yt * TM, n0 = xt * TN;
  const int lane = tid & 63, w = tid >> 6;
  const int wm = w >> 1, wn = w & 1;
  const int g = lane >> 5, lr = lane & 31;

  // staging mapping: issue i covers rows i*64 + (tid>>2), 16B slot tid&3,
  // source pre-swizzled so LDS slot s of row r holds k-chunk s ^ ((r>>1)&3)
  const int str = tid >> 2, sts = tid & 3;
  long aoff[2], boff[2];
#pragma unroll
  for (int i = 0; i < 2; i++) {
    const int rw = i * 64 + str;
    const int swc = (sts ^ ((rw >> 1) & 3)) * 8;
    aoff[i] = (long)min(m0 + rw, M - 1) * ldA + swc;
    boff[i] = (long)min(n0 + rw, N - 1) * ldB + swc;
  }
  const unsigned short* Ap[3];
  const unsigned short* Bp[3];
  Ap[0] = A0 + bz * sA; Bp[0] = B0 + bz * sB;
  Ap[1] = A1 + bz * sA; Bp[1] = B1 + bz * sB;
  Ap[2] = (NSPLIT == 3) ? A2 + bz * sA : Ap[0];
  Bp[2] = (NSPLIT == 3) ? B2 + bz * sB : Bp[0];

  f32x16 acc[2][2];
#pragma unroll
  for (int i = 0; i < 2; i++)
#pragma unroll
    for (int j = 0; j < 2; j++)
#pragma unroll
      for (int e = 0; e < 16; e++) acc[i][j][e] = 0.f;

  for (int k0 = 0; k0 < K; k0 += TK) {
#pragma unroll
    for (int p = 0; p < NSPLIT; p++)
#pragma unroll
      for (int i = 0; i < 2; i++) {
        gload_lds16(Ap[p] + aoff[i] + k0, (char*)&As[p][0] + i * 4096 + tid * 16);
        gload_lds16(Bp[p] + boff[i] + k0, (char*)&Bs[p][0] + i * 4096 + tid * 16);
      }
    __syncthreads();
#pragma unroll
    for (int kk = 0; kk < 2; kk++) {
      short8 af[2][3], bf[2][3];
#pragma unroll
      for (int i = 0; i < 2; i++) {
        const int rowa = wm * 64 + i * 32 + lr;
        const int sla = ((kk * 2 + g) ^ ((rowa >> 1) & 3)) * 8;
#pragma unroll
        for (int p = 0; p < NSPLIT; p++)
          af[i][p] = *(const short8*)&As[p][rowa * 32 + sla];
        const int rowb = wn * 64 + i * 32 + lr;
        const int slb = ((kk * 2 + g) ^ ((rowb >> 1) & 3)) * 8;
#pragma unroll
        for (int p = 0; p < NSPLIT; p++)
          bf[i][p] = *(const short8*)&Bs[p][rowb * 32 + slb];
      }
#pragma unroll
      for (int i = 0; i < 2; i++)
#pragma unroll
        for (int j = 0; j < 2; j++) {
          acc[i][j] = __builtin_amdgcn_mfma_f32_32x32x16_bf16(af[i][0], bf[j][0], acc[i][j], 0, 0, 0);
          acc[i][j] = __builtin_amdgcn_mfma_f32_32x32x16_bf16(af[i][0], bf[j][1], acc[i][j], 0, 0, 0);
          acc[i][j] = __builtin_amdgcn_mfma_f32_32x32x16_bf16(af[i][1], bf[j][0], acc[i][j], 0, 0, 0);
          if (NSPLIT == 3) {
            acc[i][j] = __builtin_amdgcn_mfma_f32_32x32x16_bf16(af[i][1], bf[j][1], acc[i][j], 0, 0, 0);
            acc[i][j] = __builtin_amdgcn_mfma_f32_32x32x16_bf16(af[i][0], bf[j][2], acc[i][j], 0, 0, 0);
            acc[i][j] = __builtin_amdgcn_mfma_f32_32x32x16_bf16(af[i][2], bf[j][0], acc[i][j], 0, 0, 0);
          }
        }
    }
    __syncthreads();
  }

  // epilogue: row = m0+wm*64+i*32 + rq*8 + g*4 + t ; col = n0+wn*64+j*32+lr
#pragma unroll
  for (int i = 0; i < 2; i++)
#pragma unroll
    for (int j = 0; j < 2; j++) {
      const int cb = n0 + wn * 64 + j * 32;
      const int col = cb + lr;
#pragma unroll
      for (int rq = 0; rq < 4; rq++)
#pragma unroll
        for (int t = 0; t < 4; t++) {
          const int reg = rq * 4 + t;
          const int row = m0 + wm * 64 + i * 32 + rq * 8 + g * 4 + t;
          float v = acc[i][j][reg];
          if (MODE == 0) {  // XC: relu, 3-plane xcT [n][c] + bf16 xc_cn [c][n]
            if (row < M) {
              v += bias[col];
              v = fmaxf(v, 0.f);
              const unsigned short h = f2bf(v); const float hf = bf2f(h);
              const unsigned short m_ = f2bf(v - hf); const float mf = bf2f(m_);
              const unsigned short l = f2bf(v - hf - mf);
              const long o = bz * sP + (long)row * 512 + col;
              P0[o] = h; P1[o] = m_; P2[o] = l;
              xcn[bz * sXcn + (long)col * 1600 + row] = h;
            }
          } else if (MODE == 1) {  // QKV
            if (row < M) {
              v += bias[col];
              if (cb < 512) {
                const unsigned short h = f2bf(v); const float hf = bf2f(h);
                const unsigned short m_ = f2bf(v - hf); const float mf = bf2f(m_);
                const unsigned short l = f2bf(v - hf - mf);
                const long o = bz * sP + (long)row * 512 + col;
                P0[o] = h; P1[o] = m_; P2[o] = l;
              } else if (cb < 1024) {
                const unsigned short h = f2bf(v); const float hf = bf2f(h);
                const unsigned short m_ = f2bf(v - hf); const float mf = bf2f(m_);
                const unsigned short l = f2bf(v - hf - mf);
                const long o = bz * sR + (long)row * 512 + (col - 512);
                R0[o] = h; R1[o] = m_; R2[o] = l;
              } else {
                const unsigned short h = f2bf(v);
                const unsigned short l = f2bf(v - bf2f(h));
                const long o = bz * sV + (long)(col - 1024) * 1600 + row;
                V0[o] = h; V1[o] = l;
              }
            }
          } else if (MODE == 2) {  // S
            if (row < M && col < N)
              outF[bz * sOutF + (long)row * 1600 + col] = v * alpha;
          } else {  // OUT: += residual
            if (col < N) {
              v += bf2f(xcn[bz * sXcn + (long)row * 1600 + col]);
              outF[bz * sOutF + (long)row * 1600 + col] = v;
            }
          }
        }
    }
}

// x [B][C][N] f32 -> xT planes [B][N][C] bf16 h/m/l
__global__ __launch_bounds__(256) void transpose_split_x(
    const float* __restrict__ x, unsigned short* __restrict__ X0,
    unsigned short* __restrict__ X1, unsigned short* __restrict__ X2)
{
  __shared__ float t[32][33];
  const int bz = blockIdx.z;
  const int n0 = blockIdx.x * 32, c0 = blockIdx.y * 32;
  const int tx = threadIdx.x & 31, ty = threadIdx.x >> 5;
  const float* xb = x + (long)bz * 512 * 1600;
#pragma unroll
  for (int k = 0; k < 4; k++)
    t[ty + k * 8][tx] = xb[(long)(c0 + ty + k * 8) * 1600 + n0 + tx];
  __syncthreads();
  const long ob = (long)bz * 1600 * 512;
#pragma unroll
  for (int k = 0; k < 4; k++) {
    const float v = t[tx][ty + k * 8];
    const unsigned short h = f2bf(v); const float hf = bf2f(h);
    const unsigned short m_ = f2bf(v - hf); const float mf = bf2f(m_);
    const unsigned short l = f2bf(v - hf - mf);
    const long o = ob + (long)(n0 + ty + k * 8) * 512 + c0 + tx;
    X0[o] = h; X1[o] = m_; X2[o] = l;
  }
}

__global__ __launch_bounds__(256) void split3_mat(
    const float* __restrict__ W, unsigned short* __restrict__ H,
    unsigned short* __restrict__ Mp, unsigned short* __restrict__ L, int n)
{
  const int i = blockIdx.x * 256 + threadIdx.x;
  if (i < n) {
    const float v = W[i];
    const unsigned short h = f2bf(v); const float hf = bf2f(h);
    const unsigned short m_ = f2bf(v - hf); const float mf = bf2f(m_);
    H[i] = h; Mp[i] = m_; L[i] = f2bf(v - hf - mf);
  }
}

// W' = W2 @ W1 (512^3, fp32 vector), split-written into planes at row offset
__global__ __launch_bounds__(256) void combine_gemm(
    const float* __restrict__ A, const float* __restrict__ B,
    unsigned short* __restrict__ H, unsigned short* __restrict__ Mp,
    unsigned short* __restrict__ L, int rowoff)
{
  __shared__ float As[16][68];
  __shared__ float Bs[16][68];
  const int tid = threadIdx.x;
  const int m0 = blockIdx.y * 64, n0 = blockIdx.x * 64;
  const int tx = tid & 15, ty = tid >> 4;
  float acc[4][4];
#pragma unroll
  for (int i = 0; i < 4; i++)
#pragma unroll
    for (int j = 0; j < 4; j++) acc[i][j] = 0.f;
  for (int k0 = 0; k0 < 512; k0 += 16) {
    {
      const int cA = tid & 15, r0 = tid >> 4;
#pragma unroll
      for (int l = 0; l < 4; l++)
        As[cA][r0 + 16 * l] = A[(long)(m0 + r0 + 16 * l) * 512 + (k0 + cA)];
      const int c2 = tid & 63, r2 = tid >> 6;
#pragma unroll
      for (int l = 0; l < 4; l++)
        Bs[r2 + 4 * l][c2] = B[(long)(k0 + r2 + 4 * l) * 512 + (n0 + c2)];
    }
    __syncthreads();
#pragma unroll
    for (int kk = 0; kk < 16; kk++) {
      float a[4], b[4];
#pragma unroll
      for (int i = 0; i < 4; i++) a[i] = As[kk][ty * 4 + i];
#pragma unroll
      for (int j = 0; j < 4; j++) b[j] = Bs[kk][tx * 4 + j];
#pragma unroll
      for (int i = 0; i < 4; i++)
#pragma unroll
        for (int j = 0; j < 4; j++) acc[i][j] = fmaf(a[i], b[j], acc[i][j]);
    }
    __syncthreads();
  }
#pragma unroll
  for (int i = 0; i < 4; i++) {
    const int m = rowoff + m0 + ty * 4 + i;
#pragma unroll
    for (int j = 0; j < 4; j++) {
      const int n = n0 + tx * 4 + j;
      const float v = acc[i][j];
      const unsigned short h = f2bf(v); const float hf = bf2f(h);
      const unsigned short m_ = f2bf(v - hf); const float mf = bf2f(m_);
      const long o = (long)m * 512 + n;
      H[o] = h; Mp[o] = m_; L[o] = f2bf(v - hf - mf);
    }
  }
}

__global__ __launch_bounds__(256) void bias_combine(
    const float* __restrict__ W2, const float* __restrict__ b1,
    const float* __restrict__ b2, float* __restrict__ bout)
{
  const int o = blockIdx.x * 256 + threadIdx.x;
  if (o < 512) {
    float acc = b2[o];
    for (int t = 0; t < 512; t++) acc = fmaf(W2[(long)o * 512 + t], b1[t], acc);
    bout[o] = acc;
  }
}

#define NROW 1600
#define NB 1024
#define BOFF 3392

// softmax + rank mask; reads S row fp32, writes w = attn*mask as TWO bf16 planes
// in place: row n occupies bf16[0..1599]=h, bf16[1600..3199]=l of the old fp32 row.
__global__ __launch_bounds__(256) void rowproc(float* __restrict__ S)
{
  __shared__ float sm[NROW];
  __shared__ float wmask[NROW];
  __shared__ unsigned short gidx[NROW];
  __shared__ int hist[NB];
  __shared__ int Rb[NB];
  __shared__ int scA[256];
  __shared__ int scB[256];
  __shared__ float redf[256];

  const int tid = threadIdx.x;
  float* srow = S + (long)blockIdx.x * NROW;

  float lmax = -3.4e38f;
  for (int i = tid; i < NROW; i += 256) {
    const float v = srow[i];
    sm[i] = v;
    wmask[i] = 1.f;
    lmax = fmaxf(lmax, v);
  }
  redf[tid] = lmax;
#pragma unroll
  for (int j = 0; j < NB / 256; j++) hist[tid + 256 * j] = 0;
  __syncthreads();
#pragma unroll
  for (int s = 128; s > 0; s >>= 1) {
    if (tid < s) redf[tid] = fmaxf(redf[tid], redf[tid + s]);
    __syncthreads();
  }
  const float rmax = redf[0];
  __syncthreads();

  float lsum = 0.f;
  for (int i = tid; i < NROW; i += 256) {
    const float v = sm[i];
    lsum += __expf(v - rmax);
    if (v >= 0.f) {
      unsigned u = __float_as_uint(v) & 0x7fffffffu;
      int b = (int)(u >> 18) - BOFF;
      b = max(0, min(NB - 1, b));
      atomicAdd(&hist[b], 1);
    }
  }
  redf[tid] = lsum;
  __syncthreads();
#pragma unroll
  for (int s = 128; s > 0; s >>= 1) {
    if (tid < s) redf[tid] += redf[tid + s];
    __syncthreads();
  }
  const float Z = redf[0];

  const int h0 = hist[4 * tid], h1 = hist[4 * tid + 1];
  const int h2 = hist[4 * tid + 2], h3 = hist[4 * tid + 3];
  const int local = h0 + h1 + h2 + h3;
  scA[tid] = local;
  __syncthreads();
  int* src = scA;
  int* dst = scB;
#pragma unroll
  for (int d = 1; d < 256; d <<= 1) {
    const int v = src[tid] + ((tid + d < 256) ? src[tid + d] : 0);
    dst[tid] = v;
    __syncthreads();
    int* tp = src; src = dst; dst = tp;
  }
  const int P = src[0];
  const int hi = src[tid] - local;
  Rb[4 * tid + 3] = hi;
  Rb[4 * tid + 2] = hi + h3;
  Rb[4 * tid + 1] = hi + h3 + h2;
  Rb[4 * tid + 0] = hi + h3 + h2 + h1;
  __syncthreads();

  for (int i = tid; i < NROW; i += 256) {
    const float v = sm[i];
    if (v >= 0.f) {
      unsigned u = __float_as_uint(v) & 0x7fffffffu;
      int b = (int)(u >> 18) - BOFF;
      b = max(0, min(NB - 1, b));
      gidx[atomicAdd(&Rb[b], 1)] = (unsigned short)i;
    }
  }
  __syncthreads();

  for (int p = tid; p < P; p += 256) {
    const int ip = gidx[p];
    const float vp = sm[ip];
    unsigned u = __float_as_uint(vp) & 0x7fffffffu;
    int b = (int)(u >> 18) - BOFF;
    b = max(0, min(NB - 1, b));
    const int end = Rb[b];
    const int start = end - hist[b];
    int cnt = 0;
    for (int qq = start; qq < end; qq++) {
      const int iq = gidx[qq];
      const float vq = sm[iq];
      cnt += (int)((vq > vp) || ((vq == vp) && (iq < ip)));
    }
    const float r1 = (float)(start + cnt + 1);
    wmask[ip] = r1 * r1 * r1;
  }
  __syncthreads();

  const float invZ = 1.f / Z;
  unsigned short* wrow = (unsigned short*)srow;
  for (int i = tid; i < NROW; i += 256) {
    const float val = __expf(sm[i] - rmax) * invZ * wmask[i];
    const unsigned short h = f2bf(val);
    wrow[i] = h;
    wrow[NROW + i] = f2bf(val - bf2f(h));
  }
}

extern "C" void kernel_launch(void* const* d_in, const int* in_sizes, int n_in,
                              void* d_out, int out_size, void* d_ws, size_t ws_size,
                              hipStream_t stream)
{
  const float scale = 0.04419417382415922f;  // 1/sqrt(512)
  const long sCN = 819200L;                  // 512*1600
  const long sNN = 2560000L;                 // 1600*1600
  const long ePlane = 8L * sCN;              // elems per bf16 plane (batched)

  const float* x   = (const float*)d_in[0];
  const float* Wc  = (const float*)d_in[1];
  const float* bc  = (const float*)d_in[2];
  const float* Wq1 = (const float*)d_in[3];
  const float* bq1 = (const float*)d_in[4];
  const float* Wq2 = (const float*)d_in[5];
  const float* bq2 = (const float*)d_in[6];
  const float* Wk1 = (const float*)d_in[7];
  const float* bk1 = (const float*)d_in[8];
  const float* Wk2 = (const float*)d_in[9];
  const float* bk2 = (const float*)d_in[10];
  const float* Wv1 = (const float*)d_in[11];
  const float* bv1 = (const float*)d_in[12];
  const float* Wv2 = (const float*)d_in[13];
  const float* bv2 = (const float*)d_in[14];
  float* out = (float*)d_out;

  char* p = (char*)d_ws;
  auto carve = [&](size_t bytes) { char* r = p; p += (bytes + 255) & ~255UL; return r; };

  float* S = (float*)carve(8L * sNN * 4);  // S fp32; also hosts xT planes early, w planes late
  unsigned short* Xh = (unsigned short*)S;
  unsigned short* Xm = Xh + ePlane;
  unsigned short* Xl = Xm + ePlane;
  unsigned short* xcTh = (unsigned short*)carve(ePlane * 2);
  unsigned short* xcTm = (unsigned short*)carve(ePlane * 2);
  unsigned short* xcTl = (unsigned short*)carve(ePlane * 2);
  unsigned short* QTh = (unsigned short*)carve(ePlane * 2);
  unsigned short* QTm = (unsigned short*)carve(ePlane * 2);
  unsigned short* QTl = (unsigned short*)carve(ePlane * 2);
  unsigned short* KTh = (unsigned short*)carve(ePlane * 2);
  unsigned short* KTm = (unsigned short*)carve(ePlane * 2);
  unsigned short* KTl = (unsigned short*)carve(ePlane * 2);
  unsigned short* Vh = (unsigned short*)carve(ePlane * 2);
  unsigned short* Vl = (unsigned short*)carve(ePlane * 2);
  unsigned short* xc_cn = (unsigned short*)carve(ePlane * 2);
  unsigned short* Wch = (unsigned short*)carve(512L * 512 * 2);
  unsigned short* Wcm = (unsigned short*)carve(512L * 512 * 2);
  unsigned short* Wcl = (unsigned short*)carve(512L * 512 * 2);
  unsigned short* Wh = (unsigned short*)carve(1536L * 512 * 2);
  unsigned short* Wm = (unsigned short*)carve(1536L * 512 * 2);
  unsigned short* Wl = (unsigned short*)carve(1536L * 512 * 2);
  float* bqkv = (float*)carve(1536L * 4);

  // prep: x transpose+split, Wc split, combined weights/biases
  transpose_split_x<<<dim3(50, 16, 8), 256, 0, stream>>>(x, Xh, Xm, Xl);
  split3_mat<<<dim3(1024), 256, 0, stream>>>(Wc, Wch, Wcm, Wcl, 512 * 512);
  combine_gemm<<<dim3(8, 8), 256, 0, stream>>>(Wq2, Wq1, Wh, Wm, Wl, 0);
  combine_gemm<<<dim3(8, 8), 256, 0, stream>>>(Wk2, Wk1, Wh, Wm, Wl, 512);
  combine_gemm<<<dim3(8, 8), 256, 0, stream>>>(Wv2, Wv1, Wh, Wm, Wl, 1024);
  bias_combine<<<dim3(2), 256, 0, stream>>>(Wq2, bq1, bq2, bqkv);
  bias_combine<<<dim3(2), 256, 0, stream>>>(Wk2, bk1, bk2, bqkv + 512);
  bias_combine<<<dim3(2), 256, 0, stream>>>(Wv2, bv1, bv2, bqkv + 1024);

  // xc = relu(xT . Wc^T + bc): [1600][512], writes xcT planes + xc_cn
  mfma_gemm<3, 0><<<dim3(4 * 13 * 8), 256, 0, stream>>>(
      Xh, Xm, Xl, Wch, Wcm, Wcl, 4, 13, 1600, 512, 512, 512, 512, sCN, 0L, bc, 1.f,
      nullptr, 0L, xcTh, xcTm, xcTl, sCN,
      nullptr, nullptr, nullptr, 0L, nullptr, nullptr, 0L, xc_cn, sCN);

  // fused QKV: [1600][1536]
  mfma_gemm<3, 1><<<dim3(12 * 13 * 8), 256, 0, stream>>>(
      xcTh, xcTm, xcTl, Wh, Wm, Wl, 12, 13, 1600, 1536, 512, 512, 512, sCN, 0L, bqkv, 1.f,
      nullptr, 0L, QTh, QTm, QTl, sCN, KTh, KTm, KTl, sCN, Vh, Vl, sCN, nullptr, 0L);

  // S = scale * QT . KT^T : [1600][1600] fp32
  mfma_gemm<3, 2><<<dim3(13 * 13 * 8), 256, 0, stream>>>(
      QTh, QTm, QTl, KTh, KTm, KTl, 13, 13, 1600, 1600, 512, 512, 512, sCN, sCN, nullptr, scale,
      S, sNN, nullptr, nullptr, nullptr, 0L,
      nullptr, nullptr, nullptr, 0L, nullptr, nullptr, 0L, nullptr, 0L);

  // softmax + rank mask; writes w h/l planes in place over S
  rowproc<<<dim3(12800), 256, 0, stream>>>(S);

  // out = V . w^T + xc : [512][1600] fp32 -> d_out
  mfma_gemm<2, 3><<<dim3(13 * 4 * 8), 256, 0, stream>>>(
      Vh, Vl, nullptr, (unsigned short*)S, (unsigned short*)S + 1600, nullptr,
      13, 4, 512, 1600, 1600, 1600, 3200, sCN, 2L * sNN, nullptr, 1.f,
      out, sCN, nullptr, nullptr, nullptr, 0L,
      nullptr, nullptr, nullptr, 0L, nullptr, nullptr, 0L, xc_cn, sCN);
}